// Round 11
// baseline (43.207 us; speedup 1.0000x reference)
//
#include <hip/hip_runtime.h>

#define S_LEN 4096
#define Dh 64
#define KC_TILE 16384
#define VT_TILE 8192

typedef __attribute__((ext_vector_type(8))) short bf16x8;
typedef __attribute__((ext_vector_type(4))) short bf16x4;
typedef __attribute__((ext_vector_type(4))) float f32x4;
typedef __attribute__((ext_vector_type(16))) float f32x16;
typedef __attribute__((ext_vector_type(4))) unsigned u32x4;

__device__ __forceinline__ short f2bf(float f) {
    union { float f; unsigned u; } c; c.f = f;
    unsigned u = c.u + 0x7FFFu + ((c.u >> 16) & 1u);
    return (short)(u >> 16);
}

__device__ __forceinline__ unsigned cvt_pk(float lo, float hi) {
    unsigned r;
    asm("v_cvt_pk_bf16_f32 %0, %1, %2" : "=v"(r) : "v"(lo), "v"(hi));
    return r;
}

__device__ __forceinline__ void pl32swap(unsigned& a, unsigned& b) {
    asm("v_permlane32_swap_b32 %0, %1" : "+v"(a), "+v"(b));
}

// ---------------- prepack3: COALESCED LDS-transpose prepack.
// One block per (bh,tile). Phase 1: row-major coalesced reads of k||kr and v,
// fp32->bf16, staged to swizzled LDS. Phase 2: fragment-order gather from LDS,
// contiguous coalesced stores to ws. Same ws image format as before:
// K region (base 0), per (bh,tile): 16 chunks of 1KB; chunk c = fs*2+half;
//   lane l bytes [c*1024+l*16,+16) = K[key=half*32+(l&31)][feat fs*16+(l>>5)*8+j] (k||kr).
// V region (base vt_base), per (bh,tile): 8 chunks of 1KB; chunk c = kb*4+ks*2+eh;
//   lane l = V^T[e=eh*32+(l&31)][key kb*32+ks*16+(l>>5)*8+j].
__global__ __launch_bounds__(256) void prepack3(
    const float* __restrict__ k, const float* __restrict__ kr,
    const float* __restrict__ v, char* __restrict__ ws,
    unsigned long long vt_base)
{
    const int bh = blockIdx.x >> 6;
    const int tile = blockIdx.x & 63;
    const int t = threadIdx.x;
    const size_t rowbase = ((size_t)bh * S_LEN + tile * 64) * Dh;

    // LDS staging: Kc[key][f 0..127] bf16, off = key*256 + f*2 ^ ((key&7)<<4)  (16KB)
    //              Vt[e][key]        bf16, off = e*128  + key*2 ^ ((e&7)<<4)   (8KB)
    __shared__ __align__(16) char sKc[16384];
    __shared__ __align__(16) char sVt[8192];

    // ---- phase 1a: K||Kr row-major -> LDS (coalesced 32B chunks)
    #pragma unroll
    for (int i = 0; i < 4; ++i) {
        const int idx = t + 256 * i;           // 1024 chunks of 8 feats
        const int f8 = idx & 15;
        const int key = idx >> 4;
        const int f0 = f8 * 8;
        const float* src = (f0 < 64) ? (k + rowbase + (size_t)key * Dh + f0)
                                     : (kr + rowbase + (size_t)key * Dh + (f0 - 64));
        f32x4 a = *(const f32x4*)src;
        f32x4 b = *(const f32x4*)(src + 4);
        u32x4 w;
        w[0] = cvt_pk(a[0], a[1]); w[1] = cvt_pk(a[2], a[3]);
        w[2] = cvt_pk(b[0], b[1]); w[3] = cvt_pk(b[2], b[3]);
        const int off = key * 256 + ((f0 * 2) ^ ((key & 7) << 4));
        *(u32x4*)(sKc + off) = w;
    }
    // ---- phase 1b: V row-major -> LDS transposed (coalesced 32B chunks)
    #pragma unroll
    for (int i = 0; i < 2; ++i) {
        const int idx = t + 256 * i;           // 512 chunks of 8 e's
        const int e8 = idx & 7;
        const int key = idx >> 3;
        const int e0 = e8 * 8;
        const float* src = v + rowbase + (size_t)key * Dh + e0;
        f32x4 a = *(const f32x4*)src;
        f32x4 b = *(const f32x4*)(src + 4);
        #pragma unroll
        for (int j = 0; j < 4; ++j) {
            int e = e0 + j;
            *(short*)(sVt + e * 128 + ((key * 2) ^ ((e & 7) << 4))) = f2bf(a[j]);
        }
        #pragma unroll
        for (int j = 0; j < 4; ++j) {
            int e = e0 + 4 + j;
            *(short*)(sVt + e * 128 + ((key * 2) ^ ((e & 7) << 4))) = f2bf(b[j]);
        }
    }
    __syncthreads();

    // ---- phase 2a: K fragment-order gather -> contiguous ws stores
    char* kdst = ws + (size_t)(bh * 64 + tile) * KC_TILE;
    #pragma unroll
    for (int i = 0; i < 4; ++i) {
        const int s = t + 256 * i;             // 1024 slots of 16B
        const int c = s >> 6;
        const int l = s & 63;
        const int fs = c >> 1, half = c & 1;
        const int key = half * 32 + (l & 31);
        const int f0 = fs * 16 + (l >> 5) * 8;
        const int off = key * 256 + ((f0 * 2) ^ ((key & 7) << 4));
        u32x4 w = *(const u32x4*)(sKc + off);
        *(u32x4*)(kdst + s * 16) = w;
    }
    // ---- phase 2b: V fragment-order gather -> contiguous ws stores
    char* vdst = ws + vt_base + (size_t)(bh * 64 + tile) * VT_TILE;
    #pragma unroll
    for (int i = 0; i < 2; ++i) {
        const int s = t + 256 * i;             // 512 slots of 16B
        const int c = s >> 6;
        const int l = s & 63;
        const int kb = c >> 2, ks = (c >> 1) & 1, eh = c & 1;
        const int e = eh * 32 + (l & 31);
        const int key0 = kb * 32 + ks * 16 + (l >> 5) * 8;
        const int off = e * 128 + ((key0 * 2) ^ ((e & 7) << 4));
        u32x4 w = *(const u32x4*)(sVt + off);
        *(u32x4*)(vdst + s * 16) = w;
    }
}

// ---------------- main (unchanged from round 10): round-5 structure +
// sched_barrier-pinned 1-ahead prefetch. 1 wave/block, no main-loop barriers.
__global__ __launch_bounds__(64, 2) void swin_attn8(
    const float* __restrict__ q, const float* __restrict__ qr,
    const char* __restrict__ ws, unsigned long long vt_base,
    const int* __restrict__ hor, float* __restrict__ out)
{
    const int W = hor[0];
    const int nwg = gridDim.x;                     // BH*128, %8==0
    const int cpx = nwg >> 3;
    const int bid = blockIdx.x;
    const int wg = (bid & 7) * cpx + (bid >> 3);   // XCD-aware bijective swizzle
    const int bh = wg >> 7;
    const int q0 = (wg & 127) * 32;
    const size_t base = (size_t)bh * S_LEN * Dh;

    const int lane = threadIdx.x;
    const int hi = lane >> 5;
    const int l32 = lane & 31;

    __shared__ float sD[32];

    const int qg = q0 + l32;                       // this lane's q-row

    // ---- Q fragments (B-operand: col=q=l32, k=hi*8+j), feat concat q||qr
    bf16x8 qf[8];
    {
        const float* qrow  = q  + base + (size_t)qg * Dh;
        const float* qrrow = qr + base + (size_t)qg * Dh;
        #pragma unroll
        for (int fs = 0; fs < 8; ++fs) {
            int feat = fs * 16 + hi * 8;
            const float* src = (feat < 64) ? (qrow + feat) : (qrrow + feat - 64);
            f32x4 a = *(const f32x4*)src;
            f32x4 b = *(const f32x4*)(src + 4);
            u32x4 w;
            w[0] = cvt_pk(a[0], a[1]); w[1] = cvt_pk(a[2], a[3]);
            w[2] = cvt_pk(b[0], b[1]); w[3] = cvt_pk(b[2], b[3]);
            qf[fs] = __builtin_bit_cast(bf16x8, w);
        }
    }

    f32x16 nacc0 = {};          // out[q][e], e in [0,32)
    f32x16 nacc1 = {};          // e in [32,64)
    float dsum = 0.f;

    const int lo_key = q0 - (W - 1);
    const int kt_lo = (lo_key <= 0) ? 0 : (lo_key >> 6);
    const int kt_hi = (q0 + 31) >> 6;

    const char* Kc = ws + (size_t)(bh << 6) * KC_TILE + lane * 16;
    const char* Vt = ws + vt_base + (size_t)(bh << 6) * VT_TILE + lane * 16;

    bf16x8 kf[16];
    bf16x8 vf[8];
    {   // prologue: tile kt_lo into registers
        const char* kp = Kc + (size_t)kt_lo * KC_TILE;
        const char* vp = Vt + (size_t)kt_lo * VT_TILE;
        #pragma unroll
        for (int c = 0; c < 16; ++c) kf[c] = *(const bf16x8*)(kp + c * 1024);
        #pragma unroll
        for (int c = 0; c < 8; ++c)  vf[c] = *(const bf16x8*)(vp + c * 1024);
    }

    for (int kt = kt_lo; kt <= kt_hi; ++kt) {
        const int k0 = kt << 6;
        const int ktn = (kt < kt_hi) ? kt + 1 : kt_hi;   // clamp (last reload harmless)
        const bool dense = (k0 + 63 <= q0) && (k0 >= q0 + 32 - W);

        // ---- swapped QK^T: S^T[key][q] = mfma(A=K, B=Q), two 32-key halves
        f32x16 sac0 = {};
        f32x16 sac1 = {};
        __builtin_amdgcn_s_setprio(1);
        #pragma unroll
        for (int fs = 0; fs < 8; ++fs) {
            sac0 = __builtin_amdgcn_mfma_f32_32x32x16_bf16(kf[fs * 2],     qf[fs], sac0, 0, 0, 0);
            sac1 = __builtin_amdgcn_mfma_f32_32x32x16_bf16(kf[fs * 2 + 1], qf[fs], sac1, 0, 0, 0);
        }
        __builtin_amdgcn_s_setprio(0);

        // ---- pinned prefetch of next K tile
        __builtin_amdgcn_sched_barrier(0);
        {
            const char* kp = Kc + (size_t)ktn * KC_TILE;
            #pragma unroll
            for (int c = 0; c < 16; ++c) kf[c] = *(const bf16x8*)(kp + c * 1024);
        }
        __builtin_amdgcn_sched_barrier(0);

        // ---- per 32-key half: mask, D-sum, cvt_pk+permlane transpose, PV
        #pragma unroll
        for (int kb = 0; kb < 2; ++kb) {
            f32x16 s = kb ? sac1 : sac0;
            if (!dense) {
                #pragma unroll
                for (int r = 0; r < 16; ++r) {
                    int key = k0 + kb * 32 + (r & 3) + 8 * (r >> 2) + 4 * hi;
                    if ((unsigned)(qg - key) >= (unsigned)W) s[r] = 0.f;
                }
            }
            #pragma unroll
            for (int r = 0; r < 16; ++r) dsum += s[r];

            unsigned w0 = cvt_pk(s[0],  s[1]);
            unsigned w1 = cvt_pk(s[2],  s[3]);
            unsigned w2 = cvt_pk(s[4],  s[5]);
            unsigned w3 = cvt_pk(s[6],  s[7]);
            unsigned w4 = cvt_pk(s[8],  s[9]);
            unsigned w5 = cvt_pk(s[10], s[11]);
            unsigned w6 = cvt_pk(s[12], s[13]);
            unsigned w7 = cvt_pk(s[14], s[15]);
            pl32swap(w0, w2);
            pl32swap(w1, w3);
            pl32swap(w4, w6);
            pl32swap(w5, w7);
            u32x4 p0v = {w0, w1, w2, w3};
            u32x4 p1v = {w4, w5, w6, w7};
            bf16x8 pa0 = __builtin_bit_cast(bf16x8, p0v);
            bf16x8 pa1 = __builtin_bit_cast(bf16x8, p1v);

            __builtin_amdgcn_s_setprio(1);
            #pragma unroll
            for (int ks = 0; ks < 2; ++ks) {
                bf16x8 pa = ks ? pa1 : pa0;
                nacc0 = __builtin_amdgcn_mfma_f32_32x32x16_bf16(pa, vf[kb * 4 + ks * 2],     nacc0, 0, 0, 0);
                nacc1 = __builtin_amdgcn_mfma_f32_32x32x16_bf16(pa, vf[kb * 4 + ks * 2 + 1], nacc1, 0, 0, 0);
            }
            __builtin_amdgcn_s_setprio(0);
        }

        // ---- pinned prefetch of next V tile (vf dead after PV above)
        __builtin_amdgcn_sched_barrier(0);
        {
            const char* vp = Vt + (size_t)ktn * VT_TILE;
            #pragma unroll
            for (int c = 0; c < 8; ++c) vf[c] = *(const bf16x8*)(vp + c * 1024);
        }
        __builtin_amdgcn_sched_barrier(0);
    }

    // ---- combine D halves; broadcast rc per q-row via tiny per-wave LDS
    unsigned da = __builtin_bit_cast(unsigned, dsum);
    unsigned db = da;
    pl32swap(da, db);
    float dfull = __builtin_bit_cast(float, da) + __builtin_bit_cast(float, db);
    float rcq = 1.0f / (dfull + 1e-12f);
    if (lane < 32) sD[l32] = rcq;
    __syncthreads();
    float rcv[16];
    #pragma unroll
    for (int r = 0; r < 16; ++r)
        rcv[r] = sD[(r & 3) + 8 * (r >> 2) + 4 * hi];

    #pragma unroll
    for (int r = 0; r < 16; ++r) {
        const int qrow = q0 + (r & 3) + 8 * (r >> 2) + 4 * hi;
        float* o = out + base + (size_t)qrow * Dh + l32;
        o[0]  = nacc0[r] * rcv[r];
        o[32] = nacc1[r] * rcv[r];
    }
}

// ---------------- fallback (round-1 proven kernel) if ws too small
__global__ __launch_bounds__(256, 2) void swin_attn_fb(
    const float* __restrict__ q, const float* __restrict__ k,
    const float* __restrict__ qr, const float* __restrict__ kr,
    const float* __restrict__ v, const int* __restrict__ hor,
    float* __restrict__ out)
{
    const int W = hor[0];
    const int q0 = blockIdx.x * 128;
    const int bh = blockIdx.y;
    const size_t base = (size_t)bh * S_LEN * Dh;

    const int tid = threadIdx.x;
    const int lane = tid & 63;
    const int wv = tid >> 6;
    const int g = lane >> 4;
    const int l16 = lane & 15;

    __shared__ __align__(16) char sK[64 * 256];
    __shared__ __align__(16) char sV[64 * 128];
    __shared__ __align__(16) char sS[4][32 * 128];

    bf16x8 qf[2][4];
    #pragma unroll
    for (int rb = 0; rb < 2; ++rb) {
        int qg = q0 + wv * 32 + rb * 16 + l16;
        const float* qrow  = q  + base + (size_t)qg * Dh;
        const float* qrrow = qr + base + (size_t)qg * Dh;
        #pragma unroll
        for (int fb = 0; fb < 4; ++fb) {
            int feat = fb * 32 + g * 8;
            const float* src = (feat < 64) ? (qrow + feat) : (qrrow + (feat - 64));
            f32x4 a = *(const f32x4*)src;
            f32x4 b = *(const f32x4*)(src + 4);
            bf16x8 fr;
            #pragma unroll
            for (int j = 0; j < 4; ++j) { fr[j] = f2bf(a[j]); fr[4 + j] = f2bf(b[j]); }
            qf[rb][fb] = fr;
        }
    }

    f32x4 nacc[2][4];
    f32x4 dacc[2];
    #pragma unroll
    for (int rb = 0; rb < 2; ++rb) {
        dacc[rb] = (f32x4){0.f, 0.f, 0.f, 0.f};
        #pragma unroll
        for (int eb = 0; eb < 4; ++eb) nacc[rb][eb] = (f32x4){0.f, 0.f, 0.f, 0.f};
    }
    bf16x8 ones;
    #pragma unroll
    for (int j = 0; j < 8; ++j) ones[j] = (short)0x3F80;

    const int lo_key = q0 - (W - 1);
    const int kt_lo = (lo_key <= 0) ? 0 : (lo_key >> 6);
    const int kt_hi = (q0 + 127) >> 6;

    for (int kt = kt_lo; kt <= kt_hi; ++kt) {
        const int k0 = kt << 6;
        __syncthreads();
        #pragma unroll
        for (int i = 0; i < 4; ++i) {
            int c = tid + 256 * i;
            int row = c >> 4;
            int f0 = (c & 15) * 8;
            const float* src = (f0 < 64) ? (k  + base + (size_t)(k0 + row) * Dh + f0)
                                         : (kr + base + (size_t)(k0 + row) * Dh + (f0 - 64));
            f32x4 a = *(const f32x4*)src;
            f32x4 b = *(const f32x4*)(src + 4);
            bf16x8 w8;
            #pragma unroll
            for (int j = 0; j < 4; ++j) { w8[j] = f2bf(a[j]); w8[4 + j] = f2bf(b[j]); }
            int off = row * 256 + ((f0 * 2) ^ ((row & 7) << 4));
            *(bf16x8*)(sK + off) = w8;
        }
        #pragma unroll
        for (int i = 0; i < 4; ++i) {
            int c = tid + 256 * i;
            int e = c & 63;
            int k4 = c >> 6;
            const float* src = v + base + (size_t)(k0 + k4 * 4) * Dh + e;
            bf16x4 w4;
            w4[0] = f2bf(src[0]); w4[1] = f2bf(src[Dh]);
            w4[2] = f2bf(src[2 * Dh]); w4[3] = f2bf(src[3 * Dh]);
            int off = e * 128 + ((k4 * 8) ^ ((e & 7) << 4));
            *(bf16x4*)(sV + off) = w4;
        }
        __syncthreads();

        const bool dense = (k0 + 63 <= q0) && (k0 >= q0 + 128 - W);
        #pragma unroll
        for (int kb = 0; kb < 4; ++kb) {
            bf16x8 kf[4];
            const int key = kb * 16 + l16;
            const int rowoff = key * 256;
            const int sw = (key & 7) << 4;
            #pragma unroll
            for (int fb = 0; fb < 4; ++fb)
                kf[fb] = *(const bf16x8*)(sK + rowoff + ((fb * 64 + g * 16) ^ sw));
            #pragma unroll
            for (int rb = 0; rb < 2; ++rb) {
                f32x4 s = {0.f, 0.f, 0.f, 0.f};
                #pragma unroll
                for (int fb = 0; fb < 4; ++fb)
                    s = __builtin_amdgcn_mfma_f32_16x16x32_bf16(qf[rb][fb], kf[fb], s, 0, 0, 0);
                const int qrow0 = rb * 16 + g * 4;
                const int qg0 = q0 + wv * 32 + qrow0;
                const int mg = k0 + kb * 16 + l16;
                if (!dense) {
                    #pragma unroll
                    for (int r = 0; r < 4; ++r) {
                        unsigned d = (unsigned)(qg0 + r - mg);
                        if (d >= (unsigned)W) s[r] = 0.f;
                    }
                }
                #pragma unroll
                for (int r = 0; r < 4; ++r) {
                    int row = qrow0 + r;
                    int off = row * 128 + (((kb * 16 + l16) * 2) ^ ((row & 7) << 4));
                    *(short*)(sS[wv] + off) = f2bf(s[r]);
                }
            }
        }
        #pragma unroll
        for (int kb2 = 0; kb2 < 2; ++kb2) {
            bf16x8 af[2];
            #pragma unroll
            for (int rb = 0; rb < 2; ++rb) {
                int row = rb * 16 + l16;
                int off = row * 128 + ((kb2 * 64 + g * 16) ^ ((row & 7) << 4));
                af[rb] = *(const bf16x8*)(sS[wv] + off);
            }
            #pragma unroll
            for (int rb = 0; rb < 2; ++rb)
                dacc[rb] = __builtin_amdgcn_mfma_f32_16x16x32_bf16(af[rb], ones, dacc[rb], 0, 0, 0);
            #pragma unroll
            for (int eb = 0; eb < 4; ++eb) {
                int e = eb * 16 + l16;
                int off = e * 128 + ((kb2 * 64 + g * 16) ^ ((e & 7) << 4));
                bf16x8 bfr = *(const bf16x8*)(sV + off);
                #pragma unroll
                for (int rb = 0; rb < 2; ++rb)
                    nacc[rb][eb] = __builtin_amdgcn_mfma_f32_16x16x32_bf16(af[rb], bfr, nacc[rb][eb], 0, 0, 0);
            }
        }
    }

    #pragma unroll
    for (int rb = 0; rb < 2; ++rb) {
        f32x4 rc;
        #pragma unroll
        for (int r = 0; r < 4; ++r) rc[r] = 1.0f / (dacc[rb][r] + 1e-12f);
        const int qg0 = q0 + wv * 32 + rb * 16 + g * 4;
        #pragma unroll
        for (int eb = 0; eb < 4; ++eb) {
            #pragma unroll
            for (int r = 0; r < 4; ++r) {
                out[base + (size_t)(qg0 + r) * Dh + eb * 16 + l16] = nacc[rb][eb][r] * rc[r];
            }
        }
    }
}

extern "C" void kernel_launch(void* const* d_in, const int* in_sizes, int n_in,
                              void* d_out, int out_size, void* d_ws, size_t ws_size,
                              hipStream_t stream) {
    const float* q  = (const float*)d_in[0];
    const float* k  = (const float*)d_in[1];
    const float* qr = (const float*)d_in[2];
    const float* kr = (const float*)d_in[3];
    const float* v  = (const float*)d_in[4];
    const int* hor  = (const int*)d_in[5];
    float* out = (float*)d_out;

    const int BH = in_sizes[0] / (S_LEN * Dh);                       // 16
    const unsigned long long vt_base = (unsigned long long)BH * 64 * KC_TILE;
    const unsigned long long ws_need = (unsigned long long)BH * 64 * (KC_TILE + VT_TILE);

    if (ws_size >= ws_need) {
        hipLaunchKernelGGL(prepack3, dim3(BH * 64), dim3(256), 0, stream,
                           k, kr, v, (char*)d_ws, vt_base);
        hipLaunchKernelGGL(swin_attn8, dim3(BH * 128), dim3(64), 0, stream,
                           q, qr, (const char*)d_ws, vt_base, hor, out);
    } else {
        hipLaunchKernelGGL(swin_attn_fb, dim3(S_LEN / 128, BH), dim3(256), 0, stream,
                           q, k, qr, kr, v, hor, out);
    }
}

// Round 12
// 41.118 us; speedup vs baseline: 1.0508x; 1.0508x over previous
//
#include <hip/hip_runtime.h>

#define S_LEN 4096
#define Dh 64
#define KC_TILE 16384
#define VT_TILE 8192

typedef __attribute__((ext_vector_type(8))) short bf16x8;
typedef __attribute__((ext_vector_type(4))) short bf16x4;
typedef __attribute__((ext_vector_type(4))) float f32x4;
typedef __attribute__((ext_vector_type(16))) float f32x16;
typedef __attribute__((ext_vector_type(4))) unsigned u32x4;

__device__ __forceinline__ short f2bf(float f) {
    union { float f; unsigned u; } c; c.f = f;
    unsigned u = c.u + 0x7FFFu + ((c.u >> 16) & 1u);
    return (short)(u >> 16);
}

__device__ __forceinline__ unsigned cvt_pk(float lo, float hi) {
    unsigned r;
    asm("v_cvt_pk_bf16_f32 %0, %1, %2" : "=v"(r) : "v"(lo), "v"(hi));
    return r;
}

__device__ __forceinline__ void pl32swap(unsigned& a, unsigned& b) {
    asm("v_permlane32_swap_b32 %0, %1" : "+v"(a), "+v"(b));
}

__device__ __forceinline__ void gload16(const void* g, void* l) {
    __builtin_amdgcn_global_load_lds(
        (const __attribute__((address_space(1))) unsigned int*)g,
        (__attribute__((address_space(3))) unsigned int*)l, 16, 0, 0);
}

// ---------------- prepack3 (unchanged from round 11): coalesced LDS-transpose prepack.
// ws image format:
// K region (base 0), per (bh,tile): 16 chunks of 1KB; chunk c = fs*2+half;
//   lane l bytes [c*1024+l*16,+16) = K[key=half*32+(l&31)][feat fs*16+(l>>5)*8+j] (k||kr).
// V region (base vt_base), per (bh,tile): 8 chunks of 1KB; chunk c = kb*4+ks*2+eh;
//   lane l = V^T[e=eh*32+(l&31)][key kb*32+ks*16+(l>>5)*8+j].
__global__ __launch_bounds__(256) void prepack3(
    const float* __restrict__ k, const float* __restrict__ kr,
    const float* __restrict__ v, char* __restrict__ ws,
    unsigned long long vt_base)
{
    const int bh = blockIdx.x >> 6;
    const int tile = blockIdx.x & 63;
    const int t = threadIdx.x;
    const size_t rowbase = ((size_t)bh * S_LEN + tile * 64) * Dh;

    __shared__ __align__(16) char sKc[16384];
    __shared__ __align__(16) char sVt[8192];

    #pragma unroll
    for (int i = 0; i < 4; ++i) {
        const int idx = t + 256 * i;
        const int f8 = idx & 15;
        const int key = idx >> 4;
        const int f0 = f8 * 8;
        const float* src = (f0 < 64) ? (k + rowbase + (size_t)key * Dh + f0)
                                     : (kr + rowbase + (size_t)key * Dh + (f0 - 64));
        f32x4 a = *(const f32x4*)src;
        f32x4 b = *(const f32x4*)(src + 4);
        u32x4 w;
        w[0] = cvt_pk(a[0], a[1]); w[1] = cvt_pk(a[2], a[3]);
        w[2] = cvt_pk(b[0], b[1]); w[3] = cvt_pk(b[2], b[3]);
        const int off = key * 256 + ((f0 * 2) ^ ((key & 7) << 4));
        *(u32x4*)(sKc + off) = w;
    }
    #pragma unroll
    for (int i = 0; i < 2; ++i) {
        const int idx = t + 256 * i;
        const int e8 = idx & 7;
        const int key = idx >> 3;
        const int e0 = e8 * 8;
        const float* src = v + rowbase + (size_t)key * Dh + e0;
        f32x4 a = *(const f32x4*)src;
        f32x4 b = *(const f32x4*)(src + 4);
        #pragma unroll
        for (int j = 0; j < 4; ++j) {
            int e = e0 + j;
            *(short*)(sVt + e * 128 + ((key * 2) ^ ((e & 7) << 4))) = f2bf(a[j]);
        }
        #pragma unroll
        for (int j = 0; j < 4; ++j) {
            int e = e0 + 4 + j;
            *(short*)(sVt + e * 128 + ((key * 2) ^ ((e & 7) << 4))) = f2bf(b[j]);
        }
    }
    __syncthreads();

    char* kdst = ws + (size_t)(bh * 64 + tile) * KC_TILE;
    #pragma unroll
    for (int i = 0; i < 4; ++i) {
        const int s = t + 256 * i;
        const int c = s >> 6;
        const int l = s & 63;
        const int fs = c >> 1, half = c & 1;
        const int key = half * 32 + (l & 31);
        const int f0 = fs * 16 + (l >> 5) * 8;
        const int off = key * 256 + ((f0 * 2) ^ ((key & 7) << 4));
        u32x4 w = *(const u32x4*)(sKc + off);
        *(u32x4*)(kdst + s * 16) = w;
    }
    char* vdst = ws + vt_base + (size_t)(bh * 64 + tile) * VT_TILE;
    #pragma unroll
    for (int i = 0; i < 2; ++i) {
        const int s = t + 256 * i;
        const int c = s >> 6;
        const int l = s & 63;
        const int kb = c >> 2, ks = (c >> 1) & 1, eh = c & 1;
        const int e = eh * 32 + (l & 31);
        const int key0 = kb * 32 + ks * 16 + (l >> 5) * 8;
        const int off = e * 128 + ((key0 * 2) ^ ((e & 7) << 4));
        u32x4 w = *(const u32x4*)(sVt + off);
        *(u32x4*)(vdst + s * 16) = w;
    }
}

// ---------------- main: HYBRID. Block = 4 waves sharing a global_load_lds
// double-buffered K/V tile pipeline (counted vmcnt, never 0 in-loop) +
// per-wave in-register compute (swapped 32x32 QK^T, cvt_pk+permlane transpose).
__global__ __launch_bounds__(256, 2) void swin_attn9(
    const float* __restrict__ q, const float* __restrict__ qr,
    const char* __restrict__ ws, unsigned long long vt_base,
    const int* __restrict__ hor, float* __restrict__ out)
{
    const int W = hor[0];
    const int nwg = gridDim.x;                     // BH*32 = 512, %8==0
    const int cpx = nwg >> 3;
    const int bid = blockIdx.x;
    const int wg = (bid & 7) * cpx + (bid >> 3);   // XCD-aware bijective swizzle
    const int bh = wg >> 5;
    const int q0 = (wg & 31) * 128;                // block covers 128 q rows
    const size_t base = (size_t)bh * S_LEN * Dh;

    const int tid = threadIdx.x;
    const int lane = tid & 63;
    const int wv = tid >> 6;                       // wave owns q rows [q0+wv*32,+32)
    const int hi = lane >> 5;
    const int l32 = lane & 31;

    __shared__ __align__(16) char sK[2][KC_TILE];  // 32KB
    __shared__ __align__(16) char sV[2][VT_TILE];  // 16KB
    __shared__ float sD[4][32];

    const int q0w = q0 + wv * 32;
    const int qg = q0w + l32;                      // this lane's q-row (B-operand col)

    // ---- Q fragments (B-operand: col=q=l32, k=hi*8+j), feat concat q||qr
    bf16x8 qf[8];
    {
        const float* qrow  = q  + base + (size_t)qg * Dh;
        const float* qrrow = qr + base + (size_t)qg * Dh;
        #pragma unroll
        for (int fs = 0; fs < 8; ++fs) {
            int feat = fs * 16 + hi * 8;
            const float* src = (feat < 64) ? (qrow + feat) : (qrrow + feat - 64);
            f32x4 a = *(const f32x4*)src;
            f32x4 b = *(const f32x4*)(src + 4);
            u32x4 w;
            w[0] = cvt_pk(a[0], a[1]); w[1] = cvt_pk(a[2], a[3]);
            w[2] = cvt_pk(b[0], b[1]); w[3] = cvt_pk(b[2], b[3]);
            qf[fs] = __builtin_bit_cast(bf16x8, w);
        }
    }

    f32x16 nacc0 = {};          // out[q][e], e in [0,32)
    f32x16 nacc1 = {};          // e in [32,64)
    float dsum = 0.f;

    // union window over the block's 128 q rows
    const int lo_key = q0 - (W - 1);
    const int kt_lo = (lo_key <= 0) ? 0 : (lo_key >> 6);
    const int kt_hi = (q0 + 127) >> 6;

    const char* KcB = ws + (size_t)(bh << 6) * KC_TILE;
    const char* VtB = ws + vt_base + (size_t)(bh << 6) * VT_TILE;

    // Drain Q/hor loads so vmcnt counts ONLY staging loads from here on.
    asm volatile("s_waitcnt vmcnt(0)" ::: "memory");
    __builtin_amdgcn_sched_barrier(0);

#define STAGE(B, KT)                                                              \
    do {                                                                          \
        const char* kg_ = KcB + (size_t)(KT) * KC_TILE + wv * 4096 + lane * 16;   \
        const char* vg_ = VtB + (size_t)(KT) * VT_TILE + wv * 2048 + lane * 16;   \
        _Pragma("unroll")                                                         \
        for (int i_ = 0; i_ < 4; ++i_)                                            \
            gload16(kg_ + i_ * 1024, &sK[B][wv * 4096 + i_ * 1024]);              \
        _Pragma("unroll")                                                         \
        for (int i_ = 0; i_ < 2; ++i_)                                            \
            gload16(vg_ + i_ * 1024, &sV[B][wv * 2048 + i_ * 1024]);              \
    } while (0)

    STAGE(0, kt_lo);    // prologue: 6 loads/thread in flight

    int buf = 0;
    for (int kt = kt_lo; kt <= kt_hi; ++kt) {
        const int k0 = kt << 6;
        if (kt < kt_hi) {
            STAGE(buf ^ 1, kt + 1);                          // 12 outstanding
            asm volatile("s_waitcnt vmcnt(6)" ::: "memory"); // cur tile landed
        } else {
            asm volatile("s_waitcnt vmcnt(0)" ::: "memory");
        }
        __builtin_amdgcn_sched_barrier(0);
        __builtin_amdgcn_s_barrier();
        asm volatile("" ::: "memory");

        const char* Kb = sK[buf];
        const char* Vb = sV[buf];
        const bool dense = (k0 + 63 <= q0w) && (k0 >= q0w + 32 - W);

        // ---- swapped QK^T from LDS: S^T[key][q] = mfma(A=K, B=Q), 2 key-halves
        f32x16 sac0 = {};
        f32x16 sac1 = {};
        __builtin_amdgcn_s_setprio(1);
        #pragma unroll
        for (int fs = 0; fs < 8; ++fs) {
            bf16x8 kf0 = *(const bf16x8*)(Kb + (fs * 2) * 1024 + lane * 16);
            bf16x8 kf1 = *(const bf16x8*)(Kb + (fs * 2 + 1) * 1024 + lane * 16);
            sac0 = __builtin_amdgcn_mfma_f32_32x32x16_bf16(kf0, qf[fs], sac0, 0, 0, 0);
            sac1 = __builtin_amdgcn_mfma_f32_32x32x16_bf16(kf1, qf[fs], sac1, 0, 0, 0);
        }
        __builtin_amdgcn_s_setprio(0);

        // ---- per 32-key half: mask, D-sum, cvt_pk+permlane transpose, PV
        #pragma unroll
        for (int kb = 0; kb < 2; ++kb) {
            f32x16 s = kb ? sac1 : sac0;
            if (!dense) {
                #pragma unroll
                for (int r = 0; r < 16; ++r) {
                    int key = k0 + kb * 32 + (r & 3) + 8 * (r >> 2) + 4 * hi;
                    if ((unsigned)(qg - key) >= (unsigned)W) s[r] = 0.f;
                }
            }
            #pragma unroll
            for (int r = 0; r < 16; ++r) dsum += s[r];

            unsigned w0 = cvt_pk(s[0],  s[1]);
            unsigned w1 = cvt_pk(s[2],  s[3]);
            unsigned w2 = cvt_pk(s[4],  s[5]);
            unsigned w3 = cvt_pk(s[6],  s[7]);
            unsigned w4 = cvt_pk(s[8],  s[9]);
            unsigned w5 = cvt_pk(s[10], s[11]);
            unsigned w6 = cvt_pk(s[12], s[13]);
            unsigned w7 = cvt_pk(s[14], s[15]);
            pl32swap(w0, w2);
            pl32swap(w1, w3);
            pl32swap(w4, w6);
            pl32swap(w5, w7);
            u32x4 p0v = {w0, w1, w2, w3};
            u32x4 p1v = {w4, w5, w6, w7};
            bf16x8 pa0 = __builtin_bit_cast(bf16x8, p0v);   // 16 keys
            bf16x8 pa1 = __builtin_bit_cast(bf16x8, p1v);   // next 16 keys

            __builtin_amdgcn_s_setprio(1);
            #pragma unroll
            for (int ks = 0; ks < 2; ++ks) {
                bf16x8 pa = ks ? pa1 : pa0;
                bf16x8 vf0 = *(const bf16x8*)(Vb + (kb * 4 + ks * 2) * 1024 + lane * 16);
                bf16x8 vf1 = *(const bf16x8*)(Vb + (kb * 4 + ks * 2 + 1) * 1024 + lane * 16);
                nacc0 = __builtin_amdgcn_mfma_f32_32x32x16_bf16(pa, vf0, nacc0, 0, 0, 0);
                nacc1 = __builtin_amdgcn_mfma_f32_32x32x16_bf16(pa, vf1, nacc1, 0, 0, 0);
            }
            __builtin_amdgcn_s_setprio(0);
        }

        asm volatile("" ::: "memory");
        __builtin_amdgcn_s_barrier();   // readers done before next STAGE overwrites
        buf ^= 1;
    }
#undef STAGE

    // ---- combine D lane-halves; broadcast rc per q-row via per-wave LDS row
    unsigned da = __builtin_bit_cast(unsigned, dsum);
    unsigned db = da;
    pl32swap(da, db);
    float dfull = __builtin_bit_cast(float, da) + __builtin_bit_cast(float, db);
    float rcq = 1.0f / (dfull + 1e-12f);
    if (lane < 32) sD[wv][l32] = rcq;
    __syncthreads();
    float rcv[16];
    #pragma unroll
    for (int r = 0; r < 16; ++r)
        rcv[r] = sD[wv][(r & 3) + 8 * (r >> 2) + 4 * hi];

    #pragma unroll
    for (int r = 0; r < 16; ++r) {
        const int qrow = q0w + (r & 3) + 8 * (r >> 2) + 4 * hi;
        float* o = out + base + (size_t)qrow * Dh + l32;
        o[0]  = nacc0[r] * rcv[r];
        o[32] = nacc1[r] * rcv[r];
    }
}

// ---------------- fallback (round-1 proven kernel) if ws too small
__global__ __launch_bounds__(256, 2) void swin_attn_fb(
    const float* __restrict__ q, const float* __restrict__ k,
    const float* __restrict__ qr, const float* __restrict__ kr,
    const float* __restrict__ v, const int* __restrict__ hor,
    float* __restrict__ out)
{
    const int W = hor[0];
    const int q0 = blockIdx.x * 128;
    const int bh = blockIdx.y;
    const size_t base = (size_t)bh * S_LEN * Dh;

    const int tid = threadIdx.x;
    const int lane = tid & 63;
    const int wv = tid >> 6;
    const int g = lane >> 4;
    const int l16 = lane & 15;

    __shared__ __align__(16) char sK[64 * 256];
    __shared__ __align__(16) char sV[64 * 128];
    __shared__ __align__(16) char sS[4][32 * 128];

    bf16x8 qf[2][4];
    #pragma unroll
    for (int rb = 0; rb < 2; ++rb) {
        int qg = q0 + wv * 32 + rb * 16 + l16;
        const float* qrow  = q  + base + (size_t)qg * Dh;
        const float* qrrow = qr + base + (size_t)qg * Dh;
        #pragma unroll
        for (int fb = 0; fb < 4; ++fb) {
            int feat = fb * 32 + g * 8;
            const float* src = (feat < 64) ? (qrow + feat) : (qrrow + (feat - 64));
            f32x4 a = *(const f32x4*)src;
            f32x4 b = *(const f32x4*)(src + 4);
            bf16x8 fr;
            #pragma unroll
            for (int j = 0; j < 4; ++j) { fr[j] = f2bf(a[j]); fr[4 + j] = f2bf(b[j]); }
            qf[rb][fb] = fr;
        }
    }

    f32x4 nacc[2][4];
    f32x4 dacc[2];
    #pragma unroll
    for (int rb = 0; rb < 2; ++rb) {
        dacc[rb] = (f32x4){0.f, 0.f, 0.f, 0.f};
        #pragma unroll
        for (int eb = 0; eb < 4; ++eb) nacc[rb][eb] = (f32x4){0.f, 0.f, 0.f, 0.f};
    }
    bf16x8 ones;
    #pragma unroll
    for (int j = 0; j < 8; ++j) ones[j] = (short)0x3F80;

    const int lo_key = q0 - (W - 1);
    const int kt_lo = (lo_key <= 0) ? 0 : (lo_key >> 6);
    const int kt_hi = (q0 + 127) >> 6;

    for (int kt = kt_lo; kt <= kt_hi; ++kt) {
        const int k0 = kt << 6;
        __syncthreads();
        #pragma unroll
        for (int i = 0; i < 4; ++i) {
            int c = tid + 256 * i;
            int row = c >> 4;
            int f0 = (c & 15) * 8;
            const float* src = (f0 < 64) ? (k  + base + (size_t)(k0 + row) * Dh + f0)
                                         : (kr + base + (size_t)(k0 + row) * Dh + (f0 - 64));
            f32x4 a = *(const f32x4*)src;
            f32x4 b = *(const f32x4*)(src + 4);
            bf16x8 w8;
            #pragma unroll
            for (int j = 0; j < 4; ++j) { w8[j] = f2bf(a[j]); w8[4 + j] = f2bf(b[j]); }
            int off = row * 256 + ((f0 * 2) ^ ((row & 7) << 4));
            *(bf16x8*)(sK + off) = w8;
        }
        #pragma unroll
        for (int i = 0; i < 4; ++i) {
            int c = tid + 256 * i;
            int e = c & 63;
            int k4 = c >> 6;
            const float* src = v + base + (size_t)(k0 + k4 * 4) * Dh + e;
            bf16x4 w4;
            w4[0] = f2bf(src[0]); w4[1] = f2bf(src[Dh]);
            w4[2] = f2bf(src[2 * Dh]); w4[3] = f2bf(src[3 * Dh]);
            int off = e * 128 + ((k4 * 8) ^ ((e & 7) << 4));
            *(bf16x4*)(sV + off) = w4;
        }
        __syncthreads();

        const bool dense = (k0 + 63 <= q0) && (k0 >= q0 + 128 - W);
        #pragma unroll
        for (int kb = 0; kb < 4; ++kb) {
            bf16x8 kf[4];
            const int key = kb * 16 + l16;
            const int rowoff = key * 256;
            const int sw = (key & 7) << 4;
            #pragma unroll
            for (int fb = 0; fb < 4; ++fb)
                kf[fb] = *(const bf16x8*)(sK + rowoff + ((fb * 64 + g * 16) ^ sw));
            #pragma unroll
            for (int rb = 0; rb < 2; ++rb) {
                f32x4 s = {0.f, 0.f, 0.f, 0.f};
                #pragma unroll
                for (int fb = 0; fb < 4; ++fb)
                    s = __builtin_amdgcn_mfma_f32_16x16x32_bf16(qf[rb][fb], kf[fb], s, 0, 0, 0);
                const int qrow0 = rb * 16 + g * 4;
                const int qg0 = q0 + wv * 32 + qrow0;
                const int mg = k0 + kb * 16 + l16;
                if (!dense) {
                    #pragma unroll
                    for (int r = 0; r < 4; ++r) {
                        unsigned d = (unsigned)(qg0 + r - mg);
                        if (d >= (unsigned)W) s[r] = 0.f;
                    }
                }
                #pragma unroll
                for (int r = 0; r < 4; ++r) {
                    int row = qrow0 + r;
                    int off = row * 128 + (((kb * 16 + l16) * 2) ^ ((row & 7) << 4));
                    *(short*)(sS[wv] + off) = f2bf(s[r]);
                }
            }
        }
        #pragma unroll
        for (int kb2 = 0; kb2 < 2; ++kb2) {
            bf16x8 af[2];
            #pragma unroll
            for (int rb = 0; rb < 2; ++rb) {
                int row = rb * 16 + l16;
                int off = row * 128 + ((kb2 * 64 + g * 16) ^ ((row & 7) << 4));
                af[rb] = *(const bf16x8*)(sS[wv] + off);
            }
            #pragma unroll
            for (int rb = 0; rb < 2; ++rb)
                dacc[rb] = __builtin_amdgcn_mfma_f32_16x16x32_bf16(af[rb], ones, dacc[rb], 0, 0, 0);
            #pragma unroll
            for (int eb = 0; eb < 4; ++eb) {
                int e = eb * 16 + l16;
                int off = e * 128 + ((kb2 * 64 + g * 16) ^ ((e & 7) << 4));
                bf16x8 bfr = *(const bf16x8*)(sV + off);
                #pragma unroll
                for (int rb = 0; rb < 2; ++rb)
                    nacc[rb][eb] = __builtin_amdgcn_mfma_f32_16x16x32_bf16(af[rb], bfr, nacc[rb][eb], 0, 0, 0);
            }
        }
    }

    #pragma unroll
    for (int rb = 0; rb < 2; ++rb) {
        f32x4 rc;
        #pragma unroll
        for (int r = 0; r < 4; ++r) rc[r] = 1.0f / (dacc[rb][r] + 1e-12f);
        const int qg0 = q0 + wv * 32 + rb * 16 + g * 4;
        #pragma unroll
        for (int eb = 0; eb < 4; ++eb) {
            #pragma unroll
            for (int r = 0; r < 4; ++r) {
                out[base + (size_t)(qg0 + r) * Dh + eb * 16 + l16] = nacc[rb][eb][r] * rc[r];
            }
        }
    }
}

extern "C" void kernel_launch(void* const* d_in, const int* in_sizes, int n_in,
                              void* d_out, int out_size, void* d_ws, size_t ws_size,
                              hipStream_t stream) {
    const float* q  = (const float*)d_in[0];
    const float* k  = (const float*)d_in[1];
    const float* qr = (const float*)d_in[2];
    const float* kr = (const float*)d_in[3];
    const float* v  = (const float*)d_in[4];
    const int* hor  = (const int*)d_in[5];
    float* out = (float*)d_out;

    const int BH = in_sizes[0] / (S_LEN * Dh);                       // 16
    const unsigned long long vt_base = (unsigned long long)BH * 64 * KC_TILE;
    const unsigned long long ws_need = (unsigned long long)BH * 64 * (KC_TILE + VT_TILE);

    if (ws_size >= ws_need) {
        hipLaunchKernelGGL(prepack3, dim3(BH * 64), dim3(256), 0, stream,
                           k, kr, v, (char*)d_ws, vt_base);
        hipLaunchKernelGGL(swin_attn9, dim3(BH * 32), dim3(256), 0, stream,
                           q, qr, (const char*)d_ws, vt_base, hor, out);
    } else {
        hipLaunchKernelGGL(swin_attn_fb, dim3(S_LEN / 128, BH), dim3(256), 0, stream,
                           q, k, qr, kr, v, hor, out);
    }
}

// Round 13
// 40.706 us; speedup vs baseline: 1.0615x; 1.0101x over previous
//
#include <hip/hip_runtime.h>

#define S_LEN 4096
#define Dh 64
#define KC_TILE 16384
#define VT_TILE 8192

typedef __attribute__((ext_vector_type(8))) short bf16x8;
typedef __attribute__((ext_vector_type(4))) short bf16x4;
typedef __attribute__((ext_vector_type(4))) float f32x4;
typedef __attribute__((ext_vector_type(16))) float f32x16;
typedef __attribute__((ext_vector_type(4))) unsigned u32x4;

__device__ __forceinline__ short f2bf(float f) {
    union { float f; unsigned u; } c; c.f = f;
    unsigned u = c.u + 0x7FFFu + ((c.u >> 16) & 1u);
    return (short)(u >> 16);
}

__device__ __forceinline__ unsigned cvt_pk(float lo, float hi) {
    unsigned r;
    asm("v_cvt_pk_bf16_f32 %0, %1, %2" : "=v"(r) : "v"(lo), "v"(hi));
    return r;
}

__device__ __forceinline__ void pl32swap(unsigned& a, unsigned& b) {
    asm("v_permlane32_swap_b32 %0, %1" : "+v"(a), "+v"(b));
}

__device__ __forceinline__ void gload16(const void* g, void* l) {
    __builtin_amdgcn_global_load_lds(
        (const __attribute__((address_space(1))) unsigned int*)g,
        (__attribute__((address_space(3))) unsigned int*)l, 16, 0, 0);
}

// ---------------- prepack3 (unchanged, proven): coalesced LDS-transpose prepack.
// ws image format:
// K region (base 0), per (bh,tile): 16 chunks of 1KB; chunk c = fs*2+half;
//   lane l bytes [c*1024+l*16,+16) = K[key=half*32+(l&31)][feat fs*16+(l>>5)*8+j] (k||kr).
// V region (base vt_base), per (bh,tile): 8 chunks of 1KB; chunk c = kb*4+ks*2+eh;
//   lane l = V^T[e=eh*32+(l&31)][key kb*32+ks*16+(l>>5)*8+j].
__global__ __launch_bounds__(256) void prepack3(
    const float* __restrict__ k, const float* __restrict__ kr,
    const float* __restrict__ v, char* __restrict__ ws,
    unsigned long long vt_base)
{
    const int bh = blockIdx.x >> 6;
    const int tile = blockIdx.x & 63;
    const int t = threadIdx.x;
    const size_t rowbase = ((size_t)bh * S_LEN + tile * 64) * Dh;

    __shared__ __align__(16) char sKc[16384];
    __shared__ __align__(16) char sVt[8192];

    #pragma unroll
    for (int i = 0; i < 4; ++i) {
        const int idx = t + 256 * i;
        const int f8 = idx & 15;
        const int key = idx >> 4;
        const int f0 = f8 * 8;
        const float* src = (f0 < 64) ? (k + rowbase + (size_t)key * Dh + f0)
                                     : (kr + rowbase + (size_t)key * Dh + (f0 - 64));
        f32x4 a = *(const f32x4*)src;
        f32x4 b = *(const f32x4*)(src + 4);
        u32x4 w;
        w[0] = cvt_pk(a[0], a[1]); w[1] = cvt_pk(a[2], a[3]);
        w[2] = cvt_pk(b[0], b[1]); w[3] = cvt_pk(b[2], b[3]);
        const int off = key * 256 + ((f0 * 2) ^ ((key & 7) << 4));
        *(u32x4*)(sKc + off) = w;
    }
    #pragma unroll
    for (int i = 0; i < 2; ++i) {
        const int idx = t + 256 * i;
        const int e8 = idx & 7;
        const int key = idx >> 3;
        const int e0 = e8 * 8;
        const float* src = v + rowbase + (size_t)key * Dh + e0;
        f32x4 a = *(const f32x4*)src;
        f32x4 b = *(const f32x4*)(src + 4);
        #pragma unroll
        for (int j = 0; j < 4; ++j) {
            int e = e0 + j;
            *(short*)(sVt + e * 128 + ((key * 2) ^ ((e & 7) << 4))) = f2bf(a[j]);
        }
        #pragma unroll
        for (int j = 0; j < 4; ++j) {
            int e = e0 + 4 + j;
            *(short*)(sVt + e * 128 + ((key * 2) ^ ((e & 7) << 4))) = f2bf(b[j]);
        }
    }
    __syncthreads();

    char* kdst = ws + (size_t)(bh * 64 + tile) * KC_TILE;
    #pragma unroll
    for (int i = 0; i < 4; ++i) {
        const int s = t + 256 * i;
        const int c = s >> 6;
        const int l = s & 63;
        const int fs = c >> 1, half = c & 1;
        const int key = half * 32 + (l & 31);
        const int f0 = fs * 16 + (l >> 5) * 8;
        const int off = key * 256 + ((f0 * 2) ^ ((key & 7) << 4));
        u32x4 w = *(const u32x4*)(sKc + off);
        *(u32x4*)(kdst + s * 16) = w;
    }
    char* vdst = ws + vt_base + (size_t)(bh * 64 + tile) * VT_TILE;
    #pragma unroll
    for (int i = 0; i < 2; ++i) {
        const int s = t + 256 * i;
        const int c = s >> 6;
        const int l = s & 63;
        const int kb = c >> 2, ks = (c >> 1) & 1, eh = c & 1;
        const int e = eh * 32 + (l & 31);
        const int key0 = kb * 32 + ks * 16 + (l >> 5) * 8;
        const int off = e * 128 + ((key0 * 2) ^ ((e & 7) << 4));
        u32x4 w = *(const u32x4*)(sVt + off);
        *(u32x4*)(vdst + s * 16) = w;
    }
}

// ---------------- main: r12 hybrid + (a) 3 blocks/CU via launch_bounds(256,3),
// (b) wave-uniform tile skip. Block = 4 waves sharing a global_load_lds
// double-buffered K/V pipeline (counted vmcnt); per-wave in-register compute.
__global__ __launch_bounds__(256, 3) void swin_attn10(
    const float* __restrict__ q, const float* __restrict__ qr,
    const char* __restrict__ ws, unsigned long long vt_base,
    const int* __restrict__ hor, float* __restrict__ out)
{
    const int W = hor[0];
    const int nwg = gridDim.x;                     // BH*32 = 512, %8==0
    const int cpx = nwg >> 3;
    const int bid = blockIdx.x;
    const int wg = (bid & 7) * cpx + (bid >> 3);   // XCD-aware bijective swizzle
    const int bh = wg >> 5;
    const int q0 = (wg & 31) * 128;                // block covers 128 q rows
    const size_t base = (size_t)bh * S_LEN * Dh;

    const int tid = threadIdx.x;
    const int lane = tid & 63;
    const int wv = tid >> 6;                       // wave owns q rows [q0+wv*32,+32)
    const int hi = lane >> 5;
    const int l32 = lane & 31;

    __shared__ __align__(16) char sK[2][KC_TILE];  // 32KB
    __shared__ __align__(16) char sV[2][VT_TILE];  // 16KB
    __shared__ float sD[4][32];

    const int q0w = q0 + wv * 32;
    const int qg = q0w + l32;                      // this lane's q-row (B-operand col)

    // ---- Q fragments (B-operand: col=q=l32, k=hi*8+j), feat concat q||qr
    bf16x8 qf[8];
    {
        const float* qrow  = q  + base + (size_t)qg * Dh;
        const float* qrrow = qr + base + (size_t)qg * Dh;
        #pragma unroll
        for (int fs = 0; fs < 8; ++fs) {
            int feat = fs * 16 + hi * 8;
            const float* src = (feat < 64) ? (qrow + feat) : (qrrow + feat - 64);
            f32x4 a = *(const f32x4*)src;
            f32x4 b = *(const f32x4*)(src + 4);
            u32x4 w;
            w[0] = cvt_pk(a[0], a[1]); w[1] = cvt_pk(a[2], a[3]);
            w[2] = cvt_pk(b[0], b[1]); w[3] = cvt_pk(b[2], b[3]);
            qf[fs] = __builtin_bit_cast(bf16x8, w);
        }
    }

    f32x16 nacc0 = {};          // out[q][e], e in [0,32)
    f32x16 nacc1 = {};          // e in [32,64)
    float dsum = 0.f;

    // union window over the block's 128 q rows
    const int lo_key = q0 - (W - 1);
    const int kt_lo = (lo_key <= 0) ? 0 : (lo_key >> 6);
    const int kt_hi = (q0 + 127) >> 6;

    const char* KcB = ws + (size_t)(bh << 6) * KC_TILE;
    const char* VtB = ws + vt_base + (size_t)(bh << 6) * VT_TILE;

    // Drain Q/hor loads so vmcnt counts ONLY staging loads from here on.
    asm volatile("s_waitcnt vmcnt(0)" ::: "memory");
    __builtin_amdgcn_sched_barrier(0);

#define STAGE(B, KT)                                                              \
    do {                                                                          \
        const char* kg_ = KcB + (size_t)(KT) * KC_TILE + wv * 4096 + lane * 16;   \
        const char* vg_ = VtB + (size_t)(KT) * VT_TILE + wv * 2048 + lane * 16;   \
        _Pragma("unroll")                                                         \
        for (int i_ = 0; i_ < 4; ++i_)                                            \
            gload16(kg_ + i_ * 1024, &sK[B][wv * 4096 + i_ * 1024]);              \
        _Pragma("unroll")                                                         \
        for (int i_ = 0; i_ < 2; ++i_)                                            \
            gload16(vg_ + i_ * 1024, &sV[B][wv * 2048 + i_ * 1024]);              \
    } while (0)

    STAGE(0, kt_lo);    // prologue: 6 loads/thread in flight

    int buf = 0;
    for (int kt = kt_lo; kt <= kt_hi; ++kt) {
        const int k0 = kt << 6;
        if (kt < kt_hi) {
            STAGE(buf ^ 1, kt + 1);                          // 12 outstanding
            asm volatile("s_waitcnt vmcnt(6)" ::: "memory"); // cur tile landed
        } else {
            asm volatile("s_waitcnt vmcnt(0)" ::: "memory");
        }
        __builtin_amdgcn_sched_barrier(0);
        __builtin_amdgcn_s_barrier();
        asm volatile("" ::: "memory");

        // ---- wave-uniform tile skip: this wave's live keys are
        // [q0w-W+1, q0w+31]; skip compute if tile [k0,k0+63] misses it.
        const bool live = (k0 + 63 >= q0w - W + 1) && (k0 <= q0w + 31);
        if (live) {
            const char* Kb = sK[buf];
            const char* Vb = sV[buf];
            const bool dense = (k0 + 63 <= q0w) && (k0 >= q0w + 32 - W);

            // ---- swapped QK^T from LDS: S^T[key][q] = mfma(A=K, B=Q)
            f32x16 sac0 = {};
            f32x16 sac1 = {};
            __builtin_amdgcn_s_setprio(1);
            #pragma unroll
            for (int fs = 0; fs < 8; ++fs) {
                bf16x8 kf0 = *(const bf16x8*)(Kb + (fs * 2) * 1024 + lane * 16);
                bf16x8 kf1 = *(const bf16x8*)(Kb + (fs * 2 + 1) * 1024 + lane * 16);
                sac0 = __builtin_amdgcn_mfma_f32_32x32x16_bf16(kf0, qf[fs], sac0, 0, 0, 0);
                sac1 = __builtin_amdgcn_mfma_f32_32x32x16_bf16(kf1, qf[fs], sac1, 0, 0, 0);
            }
            __builtin_amdgcn_s_setprio(0);

            // ---- per 32-key half: mask, D-sum, cvt_pk+permlane transpose, PV
            #pragma unroll
            for (int kb = 0; kb < 2; ++kb) {
                f32x16 s = kb ? sac1 : sac0;
                if (!dense) {
                    #pragma unroll
                    for (int r = 0; r < 16; ++r) {
                        int key = k0 + kb * 32 + (r & 3) + 8 * (r >> 2) + 4 * hi;
                        if ((unsigned)(qg - key) >= (unsigned)W) s[r] = 0.f;
                    }
                }
                #pragma unroll
                for (int r = 0; r < 16; ++r) dsum += s[r];

                unsigned w0 = cvt_pk(s[0],  s[1]);
                unsigned w1 = cvt_pk(s[2],  s[3]);
                unsigned w2 = cvt_pk(s[4],  s[5]);
                unsigned w3 = cvt_pk(s[6],  s[7]);
                unsigned w4 = cvt_pk(s[8],  s[9]);
                unsigned w5 = cvt_pk(s[10], s[11]);
                unsigned w6 = cvt_pk(s[12], s[13]);
                unsigned w7 = cvt_pk(s[14], s[15]);
                pl32swap(w0, w2);
                pl32swap(w1, w3);
                pl32swap(w4, w6);
                pl32swap(w5, w7);
                u32x4 p0v = {w0, w1, w2, w3};
                u32x4 p1v = {w4, w5, w6, w7};
                bf16x8 pa0 = __builtin_bit_cast(bf16x8, p0v);   // 16 keys
                bf16x8 pa1 = __builtin_bit_cast(bf16x8, p1v);   // next 16 keys

                __builtin_amdgcn_s_setprio(1);
                #pragma unroll
                for (int ks = 0; ks < 2; ++ks) {
                    bf16x8 pa = ks ? pa1 : pa0;
                    bf16x8 vf0 = *(const bf16x8*)(Vb + (kb * 4 + ks * 2) * 1024 + lane * 16);
                    bf16x8 vf1 = *(const bf16x8*)(Vb + (kb * 4 + ks * 2 + 1) * 1024 + lane * 16);
                    nacc0 = __builtin_amdgcn_mfma_f32_32x32x16_bf16(pa, vf0, nacc0, 0, 0, 0);
                    nacc1 = __builtin_amdgcn_mfma_f32_32x32x16_bf16(pa, vf1, nacc1, 0, 0, 0);
                }
                __builtin_amdgcn_s_setprio(0);
            }
        }

        asm volatile("" ::: "memory");
        __builtin_amdgcn_s_barrier();   // readers done before next STAGE overwrites
        buf ^= 1;
    }
#undef STAGE

    // ---- combine D lane-halves; broadcast rc per q-row via per-wave LDS row
    unsigned da = __builtin_bit_cast(unsigned, dsum);
    unsigned db = da;
    pl32swap(da, db);
    float dfull = __builtin_bit_cast(float, da) + __builtin_bit_cast(float, db);
    float rcq = 1.0f / (dfull + 1e-12f);
    if (lane < 32) sD[wv][l32] = rcq;
    __syncthreads();
    float rcv[16];
    #pragma unroll
    for (int r = 0; r < 16; ++r)
        rcv[r] = sD[wv][(r & 3) + 8 * (r >> 2) + 4 * hi];

    #pragma unroll
    for (int r = 0; r < 16; ++r) {
        const int qrow = q0w + (r & 3) + 8 * (r >> 2) + 4 * hi;
        float* o = out + base + (size_t)qrow * Dh + l32;
        o[0]  = nacc0[r] * rcv[r];
        o[32] = nacc1[r] * rcv[r];
    }
}

// ---------------- fallback (round-1 proven kernel) if ws too small
__global__ __launch_bounds__(256, 2) void swin_attn_fb(
    const float* __restrict__ q, const float* __restrict__ k,
    const float* __restrict__ qr, const float* __restrict__ kr,
    const float* __restrict__ v, const int* __restrict__ hor,
    float* __restrict__ out)
{
    const int W = hor[0];
    const int q0 = blockIdx.x * 128;
    const int bh = blockIdx.y;
    const size_t base = (size_t)bh * S_LEN * Dh;

    const int tid = threadIdx.x;
    const int lane = tid & 63;
    const int wv = tid >> 6;
    const int g = lane >> 4;
    const int l16 = lane & 15;

    __shared__ __align__(16) char sK[64 * 256];
    __shared__ __align__(16) char sV[64 * 128];
    __shared__ __align__(16) char sS[4][32 * 128];

    bf16x8 qf[2][4];
    #pragma unroll
    for (int rb = 0; rb < 2; ++rb) {
        int qg = q0 + wv * 32 + rb * 16 + l16;
        const float* qrow  = q  + base + (size_t)qg * Dh;
        const float* qrrow = qr + base + (size_t)qg * Dh;
        #pragma unroll
        for (int fb = 0; fb < 4; ++fb) {
            int feat = fb * 32 + g * 8;
            const float* src = (feat < 64) ? (qrow + feat) : (qrrow + (feat - 64));
            f32x4 a = *(const f32x4*)src;
            f32x4 b = *(const f32x4*)(src + 4);
            bf16x8 fr;
            #pragma unroll
            for (int j = 0; j < 4; ++j) { fr[j] = f2bf(a[j]); fr[4 + j] = f2bf(b[j]); }
            qf[rb][fb] = fr;
        }
    }

    f32x4 nacc[2][4];
    f32x4 dacc[2];
    #pragma unroll
    for (int rb = 0; rb < 2; ++rb) {
        dacc[rb] = (f32x4){0.f, 0.f, 0.f, 0.f};
        #pragma unroll
        for (int eb = 0; eb < 4; ++eb) nacc[rb][eb] = (f32x4){0.f, 0.f, 0.f, 0.f};
    }
    bf16x8 ones;
    #pragma unroll
    for (int j = 0; j < 8; ++j) ones[j] = (short)0x3F80;

    const int lo_key = q0 - (W - 1);
    const int kt_lo = (lo_key <= 0) ? 0 : (lo_key >> 6);
    const int kt_hi = (q0 + 127) >> 6;

    for (int kt = kt_lo; kt <= kt_hi; ++kt) {
        const int k0 = kt << 6;
        __syncthreads();
        #pragma unroll
        for (int i = 0; i < 4; ++i) {
            int c = tid + 256 * i;
            int row = c >> 4;
            int f0 = (c & 15) * 8;
            const float* src = (f0 < 64) ? (k  + base + (size_t)(k0 + row) * Dh + f0)
                                         : (kr + base + (size_t)(k0 + row) * Dh + (f0 - 64));
            f32x4 a = *(const f32x4*)src;
            f32x4 b = *(const f32x4*)(src + 4);
            bf16x8 w8;
            #pragma unroll
            for (int j = 0; j < 4; ++j) { w8[j] = f2bf(a[j]); w8[4 + j] = f2bf(b[j]); }
            int off = row * 256 + ((f0 * 2) ^ ((row & 7) << 4));
            *(bf16x8*)(sK + off) = w8;
        }
        #pragma unroll
        for (int i = 0; i < 4; ++i) {
            int c = tid + 256 * i;
            int e = c & 63;
            int k4 = c >> 6;
            const float* src = v + base + (size_t)(k0 + k4 * 4) * Dh + e;
            bf16x4 w4;
            w4[0] = f2bf(src[0]); w4[1] = f2bf(src[Dh]);
            w4[2] = f2bf(src[2 * Dh]); w4[3] = f2bf(src[3 * Dh]);
            int off = e * 128 + ((k4 * 8) ^ ((e & 7) << 4));
            *(bf16x4*)(sV + off) = w4;
        }
        __syncthreads();

        const bool dense = (k0 + 63 <= q0) && (k0 >= q0 + 128 - W);
        #pragma unroll
        for (int kb = 0; kb < 4; ++kb) {
            bf16x8 kf[4];
            const int key = kb * 16 + l16;
            const int rowoff = key * 256;
            const int sw = (key & 7) << 4;
            #pragma unroll
            for (int fb = 0; fb < 4; ++fb)
                kf[fb] = *(const bf16x8*)(sK + rowoff + ((fb * 64 + g * 16) ^ sw));
            #pragma unroll
            for (int rb = 0; rb < 2; ++rb) {
                f32x4 s = {0.f, 0.f, 0.f, 0.f};
                #pragma unroll
                for (int fb = 0; fb < 4; ++fb)
                    s = __builtin_amdgcn_mfma_f32_16x16x32_bf16(qf[rb][fb], kf[fb], s, 0, 0, 0);
                const int qrow0 = rb * 16 + g * 4;
                const int qg0 = q0 + wv * 32 + qrow0;
                const int mg = k0 + kb * 16 + l16;
                if (!dense) {
                    #pragma unroll
                    for (int r = 0; r < 4; ++r) {
                        unsigned d = (unsigned)(qg0 + r - mg);
                        if (d >= (unsigned)W) s[r] = 0.f;
                    }
                }
                #pragma unroll
                for (int r = 0; r < 4; ++r) {
                    int row = qrow0 + r;
                    int off = row * 128 + (((kb * 16 + l16) * 2) ^ ((row & 7) << 4));
                    *(short*)(sS[wv] + off) = f2bf(s[r]);
                }
            }
        }
        #pragma unroll
        for (int kb2 = 0; kb2 < 2; ++kb2) {
            bf16x8 af[2];
            #pragma unroll
            for (int rb = 0; rb < 2; ++rb) {
                int row = rb * 16 + l16;
                int off = row * 128 + ((kb2 * 64 + g * 16) ^ ((row & 7) << 4));
                af[rb] = *(const bf16x8*)(sS[wv] + off);
            }
            #pragma unroll
            for (int rb = 0; rb < 2; ++rb)
                dacc[rb] = __builtin_amdgcn_mfma_f32_16x16x32_bf16(af[rb], ones, dacc[rb], 0, 0, 0);
            #pragma unroll
            for (int eb = 0; eb < 4; ++eb) {
                int e = eb * 16 + l16;
                int off = e * 128 + ((kb2 * 64 + g * 16) ^ ((e & 7) << 4));
                bf16x8 bfr = *(const bf16x8*)(sV + off);
                #pragma unroll
                for (int rb = 0; rb < 2; ++rb)
                    nacc[rb][eb] = __builtin_amdgcn_mfma_f32_16x16x32_bf16(af[rb], bfr, nacc[rb][eb], 0, 0, 0);
            }
        }
    }

    #pragma unroll
    for (int rb = 0; rb < 2; ++rb) {
        f32x4 rc;
        #pragma unroll
        for (int r = 0; r < 4; ++r) rc[r] = 1.0f / (dacc[rb][r] + 1e-12f);
        const int qg0 = q0 + wv * 32 + rb * 16 + g * 4;
        #pragma unroll
        for (int eb = 0; eb < 4; ++eb) {
            #pragma unroll
            for (int r = 0; r < 4; ++r) {
                out[base + (size_t)(qg0 + r) * Dh + eb * 16 + l16] = nacc[rb][eb][r] * rc[r];
            }
        }
    }
}

extern "C" void kernel_launch(void* const* d_in, const int* in_sizes, int n_in,
                              void* d_out, int out_size, void* d_ws, size_t ws_size,
                              hipStream_t stream) {
    const float* q  = (const float*)d_in[0];
    const float* k  = (const float*)d_in[1];
    const float* qr = (const float*)d_in[2];
    const float* kr = (const float*)d_in[3];
    const float* v  = (const float*)d_in[4];
    const int* hor  = (const int*)d_in[5];
    float* out = (float*)d_out;

    const int BH = in_sizes[0] / (S_LEN * Dh);                       // 16
    const unsigned long long vt_base = (unsigned long long)BH * 64 * KC_TILE;
    const unsigned long long ws_need = (unsigned long long)BH * 64 * (KC_TILE + VT_TILE);

    if (ws_size >= ws_need) {
        hipLaunchKernelGGL(prepack3, dim3(BH * 64), dim3(256), 0, stream,
                           k, kr, v, (char*)d_ws, vt_base);
        hipLaunchKernelGGL(swin_attn10, dim3(BH * 32), dim3(256), 0, stream,
                           q, qr, (const char*)d_ws, vt_base, hor, out);
    } else {
        hipLaunchKernelGGL(swin_attn_fb, dim3(S_LEN / 128, BH), dim3(256), 0, stream,
                           q, k, qr, kr, v, hor, out);
    }
}